// Round 1
// 11763.933 us; speedup vs baseline: 1.4585x; 1.4585x over previous
//
#include <hip/hip_runtime.h>
#include <math.h>

#define VV 8192
#define CC 512
#define TT 1024
#define NH 16
#define NL 12
#define HSZ 32
#define FFD 2048
#define BBATCH 8
#define MROWS (BBATCH*TT)   // 8192

typedef __attribute__((ext_vector_type(8))) short short8;   // 8 bf16 (4 VGPRs)
typedef __attribute__((ext_vector_type(4))) float f32x4;

__device__ __forceinline__ unsigned short f2bf(float x) {
    unsigned u = __float_as_uint(x);
    u += 0x7fffu + ((u >> 16) & 1u);      // round-to-nearest-even
    return (unsigned short)(u >> 16);
}
__device__ __forceinline__ float bf2f(unsigned short h) {
    return __uint_as_float((unsigned)h << 16);
}

// ---------------- embedding: x = tok[idx] + lab[idxl] + pos[t] ----------------
__global__ __launch_bounds__(128) void k_embed(const int* __restrict__ idx,
                                               const int* __restrict__ idxl,
                                               const float* __restrict__ tok,
                                               const float* __restrict__ pos,
                                               const float* __restrict__ lab,
                                               float* __restrict__ x) {
    int row = blockIdx.x;            // 0..8191  (b*T + t)
    int t = row & (TT - 1);
    int c = threadIdx.x * 4;         // 128 threads * 4 = 512
    int ti = idx[row], li = idxl[row];
    float4 a = *(const float4*)(tok + (size_t)ti * CC + c);
    float4 b = *(const float4*)(lab + (size_t)li * CC + c);
    float4 p = *(const float4*)(pos + (size_t)t * CC + c);
    float4 r;
    r.x = a.x + b.x + p.x; r.y = a.y + b.y + p.y;
    r.z = a.z + b.z + p.z; r.w = a.w + b.w + p.w;
    *(float4*)(x + (size_t)row * CC + c) = r;
}

// ---------------- layernorm: one wave per row of 512 ----------------
__global__ __launch_bounds__(256) void k_ln(const float* __restrict__ x,
                                            const float* __restrict__ g,
                                            const float* __restrict__ b,
                                            float* __restrict__ y) {
    int wave = threadIdx.x >> 6;
    int lane = threadIdx.x & 63;
    int row = blockIdx.x * 4 + wave;
    const float* xr = x + (size_t)row * CC + lane * 8;
    float v[8];
    *(float4*)(v)     = *(const float4*)(xr);
    *(float4*)(v + 4) = *(const float4*)(xr + 4);
    float s = 0.f, sq = 0.f;
#pragma unroll
    for (int i = 0; i < 8; i++) { s += v[i]; sq += v[i] * v[i]; }
#pragma unroll
    for (int off = 32; off; off >>= 1) {
        s  += __shfl_xor(s,  off);
        sq += __shfl_xor(sq, off);
    }
    float mean = s * (1.f / CC);
    float var  = sq * (1.f / CC) - mean * mean;
    float inv  = rsqrtf(var + 1e-5f);
    float gv[8], bv[8];
    *(float4*)(gv)     = *(const float4*)(g + lane * 8);
    *(float4*)(gv + 4) = *(const float4*)(g + lane * 8 + 4);
    *(float4*)(bv)     = *(const float4*)(b + lane * 8);
    *(float4*)(bv + 4) = *(const float4*)(b + lane * 8 + 4);
    float o[8];
#pragma unroll
    for (int i = 0; i < 8; i++) o[i] = (v[i] - mean) * inv * gv[i] + bv[i];
    float* yr = y + (size_t)row * CC + lane * 8;
    *(float4*)(yr)     = *(const float4*)(o);
    *(float4*)(yr + 4) = *(const float4*)(o + 4);
}

// ---------------- split-bf16 MFMA GEMM ----------------------------------------
// C[M,N] = A[M,K] @ B (+bias, opt relu, opt +=C). fp32 in/out; internally each
// operand is split  x = hi(bf16) + lo(bf16)  and D accumulates
// hi*hi + hi*lo + lo*hi in fp32 MFMA -> ~2^-16 relative error (fp32-equivalent).
// LAYB==0: B row-major [K,N].  LAYB==1: qkv layout, col n=(h*32+d) at
//          B[h*(K*32) + k*32 + d].
// Tile: 128x128, BK=32, 4 waves (2x2), each wave 64x64 = 4x4 frags of 16x16x32.
// LDS layout per operand: [k-octet 0..3][row 0..127][8 bf16]  (k-contiguous 16B
// per lane -> fragment read is one ds_read_b128, conflict-free). +16-ushort
// plane pad staggers staging-write banks.
#define KPLANE 1040   // ushorts per k-octet plane: 128*8 + 16 pad

template<int RELU, int ADD, int LAYB>
__global__ __launch_bounds__(256, 2) void k_gemm(const float* __restrict__ A,
                                                 const float* __restrict__ B,
                                                 const float* __restrict__ bias,
                                                 float* __restrict__ Cout,
                                                 int Mi, int Ni, int Ki) {
    __shared__ unsigned short Ah[4 * KPLANE], Al[4 * KPLANE],
                              Bh[4 * KPLANE], Bl[4 * KPLANE];
    const int tid  = threadIdx.x;
    const int bm   = blockIdx.y * 128;
    const int bn   = blockIdx.x * 128;
    const int lane = tid & 63;
    const int w    = tid >> 6;
    const int wm   = (w >> 1) * 64;
    const int wn   = (w & 1) * 64;
    const int l15  = lane & 15;
    const int kgl  = lane >> 4;          // k-octet this lane reads

    // ---- staging geometry (computed once) ----
    // A: 4 float4 loads; position p = tid + 256*i -> row m=p>>3, float4-col c4=p&7
    size_t abase[4]; int aoff[4];
#pragma unroll
    for (int i = 0; i < 4; i++) {
        int p = tid + 256 * i, m = p >> 3, c4 = p & 7;
        abase[i] = (size_t)(bm + m) * Ki + c4 * 4;
        aoff[i]  = (c4 >> 1) * KPLANE + m * 8 + (c4 & 1) * 4;
    }
    // B: 2 slots; s = tid + 256*i -> k-octet kgs=s>>7, col n=s&127
    size_t bbase[2]; int boff[2];
#pragma unroll
    for (int i = 0; i < 2; i++) {
        int s = tid + 256 * i, kgs = s >> 7, n = s & 127;
        if (LAYB == 0) {
            bbase[i] = (size_t)(kgs * 8) * Ni + bn + n;
        } else {
            int gn = bn + n;
            bbase[i] = (size_t)(gn >> 5) * ((size_t)Ki * 32)
                     + (size_t)(kgs * 8) * 32 + (gn & 31);
        }
        boff[i] = kgs * KPLANE + n * 8;
    }
    const size_t bstride = (LAYB == 0) ? (size_t)Ni : (size_t)32;

    int afrag[4], bfrag[4];
#pragma unroll
    for (int i = 0; i < 4; i++) {
        afrag[i] = kgl * KPLANE + (wm + i * 16 + l15) * 8;
        bfrag[i] = kgl * KPLANE + (wn + i * 16 + l15) * 8;
    }

    f32x4 acc[4][4];
#pragma unroll
    for (int i = 0; i < 4; i++)
#pragma unroll
        for (int j = 0; j < 4; j++)
#pragma unroll
            for (int r = 0; r < 4; r++) acc[i][j][r] = 0.f;

    float4 areg[4];
    float  breg[16];
    // prologue: load tile 0
#pragma unroll
    for (int i = 0; i < 4; i++) areg[i] = *(const float4*)(A + abase[i]);
#pragma unroll
    for (int i = 0; i < 2; i++)
#pragma unroll
        for (int j = 0; j < 8; j++)
            breg[i * 8 + j] = B[bbase[i] + (size_t)j * bstride];

    const int nsteps = Ki >> 5;
    for (int t = 0; t < nsteps; t++) {
        __syncthreads();                       // prev compute done reading LDS
        // ---- convert + store staged tile ----
#pragma unroll
        for (int i = 0; i < 4; i++) {
            float xs[4] = {areg[i].x, areg[i].y, areg[i].z, areg[i].w};
            ushort4 hv, lv;
            unsigned short hh[4], ll[4];
#pragma unroll
            for (int u = 0; u < 4; u++) {
                hh[u] = f2bf(xs[u]);
                ll[u] = f2bf(xs[u] - bf2f(hh[u]));
            }
            hv.x = hh[0]; hv.y = hh[1]; hv.z = hh[2]; hv.w = hh[3];
            lv.x = ll[0]; lv.y = ll[1]; lv.z = ll[2]; lv.w = ll[3];
            *(ushort4*)(&Ah[aoff[i]]) = hv;    // ds_write_b64
            *(ushort4*)(&Al[aoff[i]]) = lv;
        }
#pragma unroll
        for (int i = 0; i < 2; i++) {
            unsigned hu[4], lu[4];
#pragma unroll
            for (int j = 0; j < 4; j++) {
                float x0 = breg[i * 8 + 2 * j], x1 = breg[i * 8 + 2 * j + 1];
                unsigned short h0 = f2bf(x0), h1 = f2bf(x1);
                unsigned short q0 = f2bf(x0 - bf2f(h0)), q1 = f2bf(x1 - bf2f(h1));
                hu[j] = (unsigned)h0 | ((unsigned)h1 << 16);
                lu[j] = (unsigned)q0 | ((unsigned)q1 << 16);
            }
            uint4 hv = {hu[0], hu[1], hu[2], hu[3]};
            uint4 lv = {lu[0], lu[1], lu[2], lu[3]};
            *(uint4*)(&Bh[boff[i]]) = hv;      // ds_write_b128
            *(uint4*)(&Bl[boff[i]]) = lv;
        }
        __syncthreads();
        // ---- issue next-tile global loads (overlap with MFMA) ----
        if (t + 1 < nsteps) {
            size_t ko = (size_t)(t + 1) * 32;
#pragma unroll
            for (int i = 0; i < 4; i++)
                areg[i] = *(const float4*)(A + abase[i] + ko);
#pragma unroll
            for (int i = 0; i < 2; i++)
#pragma unroll
                for (int j = 0; j < 8; j++)
                    breg[i * 8 + j] = B[bbase[i] + (ko + j) * bstride];
        }
        // ---- fragments + MFMA ----
        short8 fah[4], fal[4], fbh[4], fbl[4];
#pragma unroll
        for (int i = 0; i < 4; i++) {
            fah[i] = *(const short8*)(&Ah[afrag[i]]);
            fal[i] = *(const short8*)(&Al[afrag[i]]);
            fbh[i] = *(const short8*)(&Bh[bfrag[i]]);
            fbl[i] = *(const short8*)(&Bl[bfrag[i]]);
        }
#pragma unroll
        for (int i = 0; i < 4; i++)
#pragma unroll
            for (int j = 0; j < 4; j++) {
                acc[i][j] = __builtin_amdgcn_mfma_f32_16x16x32_bf16(fah[i], fbh[j], acc[i][j], 0, 0, 0);
                acc[i][j] = __builtin_amdgcn_mfma_f32_16x16x32_bf16(fah[i], fbl[j], acc[i][j], 0, 0, 0);
                acc[i][j] = __builtin_amdgcn_mfma_f32_16x16x32_bf16(fal[i], fbh[j], acc[i][j], 0, 0, 0);
            }
    }

    // ---- epilogue: C/D layout col=lane&15, row=(lane>>4)*4+r ----
#pragma unroll
    for (int j = 0; j < 4; j++) {
        int col = bn + wn + j * 16 + l15;
        float bb = bias ? bias[col] : 0.f;
#pragma unroll
        for (int i = 0; i < 4; i++) {
            int row0 = bm + wm + i * 16 + kgl * 4;
#pragma unroll
            for (int r = 0; r < 4; r++) {
                float val = acc[i][j][r] + bb;
                if (RELU) val = fmaxf(val, 0.f);
                float* cp = Cout + (size_t)(row0 + r) * Ni + col;
                if (ADD) val += *cp;
                *cp = val;
            }
        }
    }
}

// ---------------- flash attention: block = (b,h, 256-query tile) --------------
__global__ __launch_bounds__(256) void k_attn(const float* __restrict__ q,
                                              const float* __restrict__ k,
                                              const float* __restrict__ v,
                                              float* __restrict__ o) {
    __shared__ float Ks[64][36];   // +4 pad: spreads staging writes over banks
    __shared__ float Vs[64][36];
    int tid = threadIdx.x;
    int bh = blockIdx.y;            // 0..127
    int b = bh >> 4, h = bh & 15;
    int q0 = blockIdx.x * 256;
    int t = q0 + tid;

    const float* qrow = q + (size_t)(b * TT + t) * CC + h * HSZ;
    float qr[32];
#pragma unroll
    for (int d = 0; d < 32; d += 4) {
        float4 qq = *(const float4*)(qrow + d);
        qr[d] = qq.x; qr[d + 1] = qq.y; qr[d + 2] = qq.z; qr[d + 3] = qq.w;
    }
    const float scale = 0.1767766952966369f;  // 1/sqrt(32)
    float m = -1e30f, l = 0.f;
    float acc[32];
#pragma unroll
    for (int d = 0; d < 32; d++) acc[d] = 0.f;

    int s_end = q0 + 256;           // block-uniform causal bound
    for (int s0 = 0; s0 < s_end; s0 += 64) {
        __syncthreads();
#pragma unroll
        for (int i = 0; i < 2; i++) {
            int j = i * 256 + tid;
            int r = j >> 3, d4 = (j & 7) * 4;
            size_t g = (size_t)(b * TT + s0 + r) * CC + h * HSZ + d4;
            *(float4*)(&Ks[r][d4]) = *(const float4*)(k + g);
            *(float4*)(&Vs[r][d4]) = *(const float4*)(v + g);
        }
        __syncthreads();
        int smax = t - s0;
        if (smax > 63) smax = 63;
        for (int ss = 0; ss <= smax; ss++) {
            float dot = 0.f;
#pragma unroll
            for (int d = 0; d < 32; d += 4) {
                float4 kk = *(const float4*)(&Ks[ss][d]);
                dot += qr[d] * kk.x + qr[d + 1] * kk.y
                     + qr[d + 2] * kk.z + qr[d + 3] * kk.w;
            }
            float xv = dot * scale;
            float mn = fmaxf(m, xv);
            float corr = __expf(m - mn);
            float p = __expf(xv - mn);
            l = l * corr + p;
            m = mn;
#pragma unroll
            for (int d = 0; d < 32; d += 4) {
                float4 vv = *(const float4*)(&Vs[ss][d]);
                acc[d]     = acc[d]     * corr + p * vv.x;
                acc[d + 1] = acc[d + 1] * corr + p * vv.y;
                acc[d + 2] = acc[d + 2] * corr + p * vv.z;
                acc[d + 3] = acc[d + 3] * corr + p * vv.w;
            }
        }
    }
    float invl = 1.f / l;
    float* orow = o + (size_t)(b * TT + t) * CC + h * HSZ;
#pragma unroll
    for (int d = 0; d < 32; d += 4) {
        float4 r;
        r.x = acc[d] * invl; r.y = acc[d + 1] * invl;
        r.z = acc[d + 2] * invl; r.w = acc[d + 3] * invl;
        *(float4*)(orow + d) = r;
    }
}

// ---------------- loss ----------------
__global__ void k_zero(float* p) { *p = 0.f; }

__global__ __launch_bounds__(256) void k_loss(const float* __restrict__ logits,
                                              const int* __restrict__ targets,
                                              float* __restrict__ loss) {
    int row = blockIdx.x;
    const float* lr = logits + (size_t)row * VV;
    int tid = threadIdx.x;
    float m = -1e30f, s = 0.f;
    for (int j = tid * 4; j < VV; j += 1024) {
        float4 xv = *(const float4*)(lr + j);
        float xs[4] = {xv.x, xv.y, xv.z, xv.w};
#pragma unroll
        for (int u = 0; u < 4; u++) {
            float mn = fmaxf(m, xs[u]);
            s = s * __expf(m - mn) + __expf(xs[u] - mn);
            m = mn;
        }
    }
#pragma unroll
    for (int off = 32; off; off >>= 1) {
        float m2 = __shfl_xor(m, off);
        float s2 = __shfl_xor(s, off);
        float mn = fmaxf(m, m2);
        s = s * __expf(m - mn) + s2 * __expf(m2 - mn);
        m = mn;
    }
    __shared__ float sm[4], ss[4];
    int wave = tid >> 6, lane = tid & 63;
    if (lane == 0) { sm[wave] = m; ss[wave] = s; }
    __syncthreads();
    if (tid == 0) {
        float M = fmaxf(fmaxf(sm[0], sm[1]), fmaxf(sm[2], sm[3]));
        float S = ss[0] * __expf(sm[0] - M) + ss[1] * __expf(sm[1] - M)
                + ss[2] * __expf(sm[2] - M) + ss[3] * __expf(sm[3] - M);
        float lt = lr[targets[row]];
        atomicAdd(loss, -(lt - M - logf(S)) * (1.0f / (float)MROWS));
    }
}

// ---------------- orchestration ----------------
extern "C" void kernel_launch(void* const* d_in, const int* in_sizes, int n_in,
                              void* d_out, int out_size, void* d_ws, size_t ws_size,
                              hipStream_t stream) {
    const int*   idx   = (const int*)d_in[0];
    const int*   idxl  = (const int*)d_in[1];
    const int*   tgt   = (const int*)d_in[2];
    const float* tok   = (const float*)d_in[3];
    const float* pos   = (const float*)d_in[4];
    const float* lab   = (const float*)d_in[5];
    const float* Wq    = (const float*)d_in[6];
    const float* Wk    = (const float*)d_in[7];
    const float* Wv    = (const float*)d_in[8];
    const float* Wo    = (const float*)d_in[9];
    const float* bo    = (const float*)d_in[10];
    const float* ln1g  = (const float*)d_in[11];
    const float* ln1b  = (const float*)d_in[12];
    const float* W1    = (const float*)d_in[13];
    const float* b1    = (const float*)d_in[14];
    const float* W2    = (const float*)d_in[15];
    const float* b2    = (const float*)d_in[16];
    const float* ln2g  = (const float*)d_in[17];
    const float* ln2b  = (const float*)d_in[18];
    const float* lnfg  = (const float*)d_in[19];
    const float* lnfb  = (const float*)d_in[20];
    const float* Wlm   = (const float*)d_in[21];
    const float* blm   = (const float*)d_in[22];
    float* out = (float*)d_out;
    float* ws  = (float*)d_ws;

    const size_t NTOK = (size_t)MROWS * CC;   // 4,194,304
    float* x  = ws;
    float* h  = x  + NTOK;
    float* qb = h  + NTOK;
    float* kb = qb + NTOK;
    float* vb = kb + NTOK;
    float* ob = vb + NTOK;
    float* ff = ob + NTOK;                    // 8192*2048

    dim3 blk(256);
    dim3 g_sq(CC / 128, MROWS / 128);         // 4  x 64
    dim3 g_ff(FFD / 128, MROWS / 128);        // 16 x 64
    dim3 g_lm(VV / 128, MROWS / 128);         // 64 x 64
    dim3 gs_at(TT / 256, BBATCH * NH);        // 4 x 128

    k_embed<<<MROWS, 128, 0, stream>>>(idx, idxl, tok, pos, lab, x);

    for (int l = 0; l < NL; l++) {
        k_ln<<<MROWS / 4, blk, 0, stream>>>(x, ln1g + l * CC, ln1b + l * CC, h);
        const size_t wqkv = (size_t)l * NH * CC * HSZ;
        k_gemm<0, 0, 1><<<g_sq, blk, 0, stream>>>(h, Wq + wqkv, nullptr, qb, MROWS, CC, CC);
        k_gemm<0, 0, 1><<<g_sq, blk, 0, stream>>>(h, Wk + wqkv, nullptr, kb, MROWS, CC, CC);
        k_gemm<0, 0, 1><<<g_sq, blk, 0, stream>>>(h, Wv + wqkv, nullptr, vb, MROWS, CC, CC);
        k_attn<<<gs_at, blk, 0, stream>>>(qb, kb, vb, ob);
        k_gemm<0, 1, 0><<<g_sq, blk, 0, stream>>>(ob, Wo + (size_t)l * CC * CC,
                                                  bo + l * CC, x, MROWS, CC, CC);
        k_ln<<<MROWS / 4, blk, 0, stream>>>(x, ln2g + l * CC, ln2b + l * CC, h);
        k_gemm<1, 0, 0><<<g_ff, blk, 0, stream>>>(h, W1 + (size_t)l * CC * FFD,
                                                  b1 + l * FFD, ff, MROWS, FFD, CC);
        k_gemm<0, 1, 0><<<g_sq, blk, 0, stream>>>(ff, W2 + (size_t)l * FFD * CC,
                                                  b2 + l * CC, x, MROWS, CC, FFD);
    }

    k_ln<<<MROWS / 4, blk, 0, stream>>>(x, lnfg, lnfb, h);
    k_gemm<0, 0, 0><<<g_lm, blk, 0, stream>>>(h, Wlm, blm, out, MROWS, VV, CC);

    float* loss_p = out + (size_t)MROWS * VV;
    k_zero<<<1, 1, 0, stream>>>(loss_p);
    k_loss<<<MROWS, blk, 0, stream>>>(out, tgt, loss_p);
}

// Round 2
// 6553.137 us; speedup vs baseline: 2.6182x; 1.7952x over previous
//
#include <hip/hip_runtime.h>
#include <math.h>

#define VV 8192
#define CC 512
#define TT 1024
#define NH 16
#define NL 12
#define HSZ 32
#define FFD 2048
#define BBATCH 8
#define MROWS (BBATCH*TT)   // 8192

typedef __attribute__((ext_vector_type(8))) short short8;   // 8 bf16 (4 VGPRs)
typedef __attribute__((ext_vector_type(4))) float f32x4;

__device__ __forceinline__ unsigned short f2bf(float x) {
    unsigned u = __float_as_uint(x);
    u += 0x7fffu + ((u >> 16) & 1u);      // round-to-nearest-even
    return (unsigned short)(u >> 16);
}
__device__ __forceinline__ float bf2f(unsigned short h) {
    return __uint_as_float((unsigned)h << 16);
}

// ---------------- embedding: x = tok[idx] + lab[idxl] + pos[t] ----------------
__global__ __launch_bounds__(128) void k_embed(const int* __restrict__ idx,
                                               const int* __restrict__ idxl,
                                               const float* __restrict__ tok,
                                               const float* __restrict__ pos,
                                               const float* __restrict__ lab,
                                               float* __restrict__ x) {
    int row = blockIdx.x;            // 0..8191  (b*T + t)
    int t = row & (TT - 1);
    int c = threadIdx.x * 4;         // 128 threads * 4 = 512
    int ti = idx[row], li = idxl[row];
    float4 a = *(const float4*)(tok + (size_t)ti * CC + c);
    float4 b = *(const float4*)(lab + (size_t)li * CC + c);
    float4 p = *(const float4*)(pos + (size_t)t * CC + c);
    float4 r;
    r.x = a.x + b.x + p.x; r.y = a.y + b.y + p.y;
    r.z = a.z + b.z + p.z; r.w = a.w + b.w + p.w;
    *(float4*)(x + (size_t)row * CC + c) = r;
}

// ---------------- layernorm: one wave per row of 512 ----------------
__global__ __launch_bounds__(256) void k_ln(const float* __restrict__ x,
                                            const float* __restrict__ g,
                                            const float* __restrict__ b,
                                            float* __restrict__ y) {
    int wave = threadIdx.x >> 6;
    int lane = threadIdx.x & 63;
    int row = blockIdx.x * 4 + wave;
    const float* xr = x + (size_t)row * CC + lane * 8;
    float v[8];
    *(float4*)(v)     = *(const float4*)(xr);
    *(float4*)(v + 4) = *(const float4*)(xr + 4);
    float s = 0.f, sq = 0.f;
#pragma unroll
    for (int i = 0; i < 8; i++) { s += v[i]; sq += v[i] * v[i]; }
#pragma unroll
    for (int off = 32; off; off >>= 1) {
        s  += __shfl_xor(s,  off);
        sq += __shfl_xor(sq, off);
    }
    float mean = s * (1.f / CC);
    float var  = sq * (1.f / CC) - mean * mean;
    float inv  = rsqrtf(var + 1e-5f);
    float gv[8], bv[8];
    *(float4*)(gv)     = *(const float4*)(g + lane * 8);
    *(float4*)(gv + 4) = *(const float4*)(g + lane * 8 + 4);
    *(float4*)(bv)     = *(const float4*)(b + lane * 8);
    *(float4*)(bv + 4) = *(const float4*)(b + lane * 8 + 4);
    float o[8];
#pragma unroll
    for (int i = 0; i < 8; i++) o[i] = (v[i] - mean) * inv * gv[i] + bv[i];
    float* yr = y + (size_t)row * CC + lane * 8;
    *(float4*)(yr)     = *(const float4*)(o);
    *(float4*)(yr + 4) = *(const float4*)(o + 4);
}

// ---------------- split-bf16 MFMA GEMM ----------------------------------------
#define KPLANE 1040   // ushorts per k-octet plane: 128*8 + 16 pad

template<int RELU, int ADD, int LAYB>
__global__ __launch_bounds__(256, 2) void k_gemm(const float* __restrict__ A,
                                                 const float* __restrict__ B,
                                                 const float* __restrict__ bias,
                                                 float* __restrict__ Cout,
                                                 int Mi, int Ni, int Ki) {
    __shared__ unsigned short Ah[4 * KPLANE], Al[4 * KPLANE],
                              Bh[4 * KPLANE], Bl[4 * KPLANE];
    const int tid  = threadIdx.x;
    const int bm   = blockIdx.y * 128;
    const int bn   = blockIdx.x * 128;
    const int lane = tid & 63;
    const int w    = tid >> 6;
    const int wm   = (w >> 1) * 64;
    const int wn   = (w & 1) * 64;
    const int l15  = lane & 15;
    const int kgl  = lane >> 4;          // k-octet this lane reads

    size_t abase[4]; int aoff[4];
#pragma unroll
    for (int i = 0; i < 4; i++) {
        int p = tid + 256 * i, m = p >> 3, c4 = p & 7;
        abase[i] = (size_t)(bm + m) * Ki + c4 * 4;
        aoff[i]  = (c4 >> 1) * KPLANE + m * 8 + (c4 & 1) * 4;
    }
    size_t bbase[2]; int boff[2];
#pragma unroll
    for (int i = 0; i < 2; i++) {
        int s = tid + 256 * i, kgs = s >> 7, n = s & 127;
        if (LAYB == 0) {
            bbase[i] = (size_t)(kgs * 8) * Ni + bn + n;
        } else {
            int gn = bn + n;
            bbase[i] = (size_t)(gn >> 5) * ((size_t)Ki * 32)
                     + (size_t)(kgs * 8) * 32 + (gn & 31);
        }
        boff[i] = kgs * KPLANE + n * 8;
    }
    const size_t bstride = (LAYB == 0) ? (size_t)Ni : (size_t)32;

    int afrag[4], bfrag[4];
#pragma unroll
    for (int i = 0; i < 4; i++) {
        afrag[i] = kgl * KPLANE + (wm + i * 16 + l15) * 8;
        bfrag[i] = kgl * KPLANE + (wn + i * 16 + l15) * 8;
    }

    f32x4 acc[4][4];
#pragma unroll
    for (int i = 0; i < 4; i++)
#pragma unroll
        for (int j = 0; j < 4; j++)
#pragma unroll
            for (int r = 0; r < 4; r++) acc[i][j][r] = 0.f;

    float4 areg[4];
    float  breg[16];
#pragma unroll
    for (int i = 0; i < 4; i++) areg[i] = *(const float4*)(A + abase[i]);
#pragma unroll
    for (int i = 0; i < 2; i++)
#pragma unroll
        for (int j = 0; j < 8; j++)
            breg[i * 8 + j] = B[bbase[i] + (size_t)j * bstride];

    const int nsteps = Ki >> 5;
    for (int t = 0; t < nsteps; t++) {
        __syncthreads();
#pragma unroll
        for (int i = 0; i < 4; i++) {
            float xs[4] = {areg[i].x, areg[i].y, areg[i].z, areg[i].w};
            ushort4 hv, lv;
            unsigned short hh[4], ll[4];
#pragma unroll
            for (int u = 0; u < 4; u++) {
                hh[u] = f2bf(xs[u]);
                ll[u] = f2bf(xs[u] - bf2f(hh[u]));
            }
            hv.x = hh[0]; hv.y = hh[1]; hv.z = hh[2]; hv.w = hh[3];
            lv.x = ll[0]; lv.y = ll[1]; lv.z = ll[2]; lv.w = ll[3];
            *(ushort4*)(&Ah[aoff[i]]) = hv;
            *(ushort4*)(&Al[aoff[i]]) = lv;
        }
#pragma unroll
        for (int i = 0; i < 2; i++) {
            unsigned hu[4], lu[4];
#pragma unroll
            for (int j = 0; j < 4; j++) {
                float x0 = breg[i * 8 + 2 * j], x1 = breg[i * 8 + 2 * j + 1];
                unsigned short h0 = f2bf(x0), h1 = f2bf(x1);
                unsigned short q0 = f2bf(x0 - bf2f(h0)), q1 = f2bf(x1 - bf2f(h1));
                hu[j] = (unsigned)h0 | ((unsigned)h1 << 16);
                lu[j] = (unsigned)q0 | ((unsigned)q1 << 16);
            }
            uint4 hv = {hu[0], hu[1], hu[2], hu[3]};
            uint4 lv = {lu[0], lu[1], lu[2], lu[3]};
            *(uint4*)(&Bh[boff[i]]) = hv;
            *(uint4*)(&Bl[boff[i]]) = lv;
        }
        __syncthreads();
        if (t + 1 < nsteps) {
            size_t ko = (size_t)(t + 1) * 32;
#pragma unroll
            for (int i = 0; i < 4; i++)
                areg[i] = *(const float4*)(A + abase[i] + ko);
#pragma unroll
            for (int i = 0; i < 2; i++)
#pragma unroll
                for (int j = 0; j < 8; j++)
                    breg[i * 8 + j] = B[bbase[i] + (ko + j) * bstride];
        }
        short8 fah[4], fal[4], fbh[4], fbl[4];
#pragma unroll
        for (int i = 0; i < 4; i++) {
            fah[i] = *(const short8*)(&Ah[afrag[i]]);
            fal[i] = *(const short8*)(&Al[afrag[i]]);
            fbh[i] = *(const short8*)(&Bh[bfrag[i]]);
            fbl[i] = *(const short8*)(&Bl[bfrag[i]]);
        }
#pragma unroll
        for (int i = 0; i < 4; i++)
#pragma unroll
            for (int j = 0; j < 4; j++) {
                acc[i][j] = __builtin_amdgcn_mfma_f32_16x16x32_bf16(fah[i], fbh[j], acc[i][j], 0, 0, 0);
                acc[i][j] = __builtin_amdgcn_mfma_f32_16x16x32_bf16(fah[i], fbl[j], acc[i][j], 0, 0, 0);
                acc[i][j] = __builtin_amdgcn_mfma_f32_16x16x32_bf16(fal[i], fbh[j], acc[i][j], 0, 0, 0);
            }
    }

#pragma unroll
    for (int j = 0; j < 4; j++) {
        int col = bn + wn + j * 16 + l15;
        float bb = bias ? bias[col] : 0.f;
#pragma unroll
        for (int i = 0; i < 4; i++) {
            int row0 = bm + wm + i * 16 + kgl * 4;
#pragma unroll
            for (int r = 0; r < 4; r++) {
                float val = acc[i][j][r] + bb;
                if (RELU) val = fmaxf(val, 0.f);
                float* cp = Cout + (size_t)(row0 + r) * Ni + col;
                if (ADD) val += *cp;
                *cp = val;
            }
        }
    }
}

// ---------------- MFMA flash attention ----------------------------------------
// Block = 4 waves, one (b,h), 64-row Q-tile (wave w owns rows w*16..w*16+15).
// kv tiles of 64 staged in LDS as split bf16 (hi+lo). All matmuls use the
// 3-term split (hh+hl+lh) -> fp32-equivalent numerics.
// Fragment conventions (HW-verified by k_gemm): A: lane=(m=l15, koct=lane>>4)
// holds A[m][koct*8..+8]; B: lane=(n=l15, koct) holds B[koct*8..+8][n];
// C/D: col=l15, row=(lane>>4)*4+r.
#define AKPL 520    // K plane stride (ushorts): 64*8 + 8
#define AVPL 264    // V^T plane stride: 32*8 + 8
#define APPL 136    // P plane stride: 16*8 + 8
#define APW  (8*APPL)

__global__ __launch_bounds__(256) void k_attn(const float* __restrict__ q,
                                              const float* __restrict__ k,
                                              const float* __restrict__ v,
                                              float* __restrict__ o) {
    __shared__ unsigned short Kh[4 * AKPL], Kl[4 * AKPL];
    __shared__ unsigned short Vh[8 * AVPL], Vl[8 * AVPL];
    __shared__ unsigned short Ph[4 * APW],  Pl[4 * APW];

    const int tid  = threadIdx.x;
    const int w    = tid >> 6;
    const int lane = tid & 63;
    const int l15  = lane & 15;
    const int kgl  = lane >> 4;
    const int bh   = blockIdx.y;
    const int b    = bh >> 4, h = bh & 15;
    const int qt0  = blockIdx.x * 64;
    const float scale = 0.1767766952966369f;   // 1/sqrt(32)

    // ---- Q fragment (scale folded in before split) ----
    const int qrow = qt0 + w * 16 + l15;
    const float* qp = q + (size_t)(b * TT + qrow) * CC + h * HSZ + kgl * 8;
    float qf[8];
    *(float4*)(qf)     = *(const float4*)(qp);
    *(float4*)(qf + 4) = *(const float4*)(qp + 4);
    short8 aqh, aql;
#pragma unroll
    for (int i = 0; i < 8; i++) {
        float xs = qf[i] * scale;
        unsigned short hh = f2bf(xs);
        aqh[i] = (short)hh;
        aql[i] = (short)f2bf(xs - bf2f(hh));
    }

    float m_[4], l_[4];
    f32x4 oa[2];
#pragma unroll
    for (int r = 0; r < 4; r++) { m_[r] = -1e30f; l_[r] = 0.f; }
#pragma unroll
    for (int dn = 0; dn < 2; dn++)
#pragma unroll
        for (int r = 0; r < 4; r++) oa[dn][r] = 0.f;

    const int ntiles = blockIdx.x + 1;
    for (int tkv = 0; tkv < ntiles; tkv++) {
        const int s0 = tkv * 64;
        __syncthreads();                       // all waves done reading K/V
        // ---- stage K (by d-octet planes) and V^T (by s-octet planes) ----
#pragma unroll
        for (int i = 0; i < 2; i++) {
            int j = i * 256 + tid;
            int s = j >> 3, d4 = (j & 7) * 4;
            size_t g = (size_t)(b * TT + s0 + s) * CC + h * HSZ + d4;
            float4 kv4 = *(const float4*)(k + g);
            float4 vv4 = *(const float4*)(v + g);
            float ksv[4] = {kv4.x, kv4.y, kv4.z, kv4.w};
            ushort4 khv, klv;
            unsigned short th[4], tl[4];
#pragma unroll
            for (int u = 0; u < 4; u++) {
                th[u] = f2bf(ksv[u]);
                tl[u] = f2bf(ksv[u] - bf2f(th[u]));
            }
            khv.x = th[0]; khv.y = th[1]; khv.z = th[2]; khv.w = th[3];
            klv.x = tl[0]; klv.y = tl[1]; klv.z = tl[2]; klv.w = tl[3];
            int ka = (d4 >> 3) * AKPL + s * 8 + (d4 & 7);
            *(ushort4*)(&Kh[ka]) = khv;
            *(ushort4*)(&Kl[ka]) = klv;
            float vsv[4] = {vv4.x, vv4.y, vv4.z, vv4.w};
            int soct = s >> 3, sj = s & 7;
#pragma unroll
            for (int u = 0; u < 4; u++) {
                unsigned short vh_ = f2bf(vsv[u]);
                unsigned short vl_ = f2bf(vsv[u] - bf2f(vh_));
                int va = soct * AVPL + (d4 + u) * 8 + sj;
                Vh[va] = vh_;
                Vl[va] = vl_;
            }
        }
        __syncthreads();
        // ---- S = Q K^T (3-term split) ----
        f32x4 sf[4];
#pragma unroll
        for (int nj = 0; nj < 4; nj++) {
#pragma unroll
            for (int r = 0; r < 4; r++) sf[nj][r] = 0.f;
            int ka = kgl * AKPL + (nj * 16 + l15) * 8;
            short8 bkh = *(const short8*)(&Kh[ka]);
            short8 bkl = *(const short8*)(&Kl[ka]);
            sf[nj] = __builtin_amdgcn_mfma_f32_16x16x32_bf16(aqh, bkh, sf[nj], 0, 0, 0);
            sf[nj] = __builtin_amdgcn_mfma_f32_16x16x32_bf16(aqh, bkl, sf[nj], 0, 0, 0);
            sf[nj] = __builtin_amdgcn_mfma_f32_16x16x32_bf16(aql, bkh, sf[nj], 0, 0, 0);
        }
        // ---- online softmax (rows = kgl*4+r of this wave's 16) ----
        float p_[4][4];
#pragma unroll
        for (int nj = 0; nj < 4; nj++) {
            int scol = s0 + nj * 16 + l15;
#pragma unroll
            for (int r = 0; r < 4; r++) {
                int qr = qt0 + w * 16 + kgl * 4 + r;
                float x = sf[nj][r];
                p_[nj][r] = (scol > qr) ? -1e30f : x;
            }
        }
#pragma unroll
        for (int r = 0; r < 4; r++) {
            float rm = fmaxf(fmaxf(p_[0][r], p_[1][r]), fmaxf(p_[2][r], p_[3][r]));
#pragma unroll
            for (int off = 8; off; off >>= 1) rm = fmaxf(rm, __shfl_xor(rm, off));
            float mn = fmaxf(m_[r], rm);
            float corr = __expf(m_[r] - mn);
            m_[r] = mn;
            float rs = 0.f;
#pragma unroll
            for (int nj = 0; nj < 4; nj++) {
                p_[nj][r] = __expf(p_[nj][r] - mn);
                rs += p_[nj][r];
            }
#pragma unroll
            for (int off = 8; off; off >>= 1) rs += __shfl_xor(rs, off);
            l_[r] = l_[r] * corr + rs;
            oa[0][r] *= corr;
            oa[1][r] *= corr;
        }
        // ---- write P (hi/lo) to per-wave LDS for the PV A-fragment ----
#pragma unroll
        for (int nj = 0; nj < 4; nj++) {
            int sl = nj * 16 + l15;
            int pa0 = w * APW + (sl >> 3) * APPL + (sl & 7);
#pragma unroll
            for (int r = 0; r < 4; r++) {
                float pv = p_[nj][r];
                unsigned short ph_ = f2bf(pv);
                unsigned short pl_ = f2bf(pv - bf2f(ph_));
                int pa = pa0 + (kgl * 4 + r) * 8;
                Ph[pa] = ph_;
                Pl[pa] = pl_;
            }
        }
        // ---- O += P V (3-term split) ----
#pragma unroll
        for (int ks = 0; ks < 2; ks++) {
            int paddr = w * APW + (ks * 4 + kgl) * APPL + l15 * 8;
            short8 pah = *(const short8*)(&Ph[paddr]);
            short8 pal = *(const short8*)(&Pl[paddr]);
#pragma unroll
            for (int dn = 0; dn < 2; dn++) {
                int va = (ks * 4 + kgl) * AVPL + (dn * 16 + l15) * 8;
                short8 bvh = *(const short8*)(&Vh[va]);
                short8 bvl = *(const short8*)(&Vl[va]);
                oa[dn] = __builtin_amdgcn_mfma_f32_16x16x32_bf16(pah, bvh, oa[dn], 0, 0, 0);
                oa[dn] = __builtin_amdgcn_mfma_f32_16x16x32_bf16(pah, bvl, oa[dn], 0, 0, 0);
                oa[dn] = __builtin_amdgcn_mfma_f32_16x16x32_bf16(pal, bvh, oa[dn], 0, 0, 0);
            }
        }
    }
    // ---- epilogue ----
    float inv[4];
#pragma unroll
    for (int r = 0; r < 4; r++) inv[r] = 1.f / l_[r];
#pragma unroll
    for (int dn = 0; dn < 2; dn++)
#pragma unroll
        for (int r = 0; r < 4; r++) {
            int qr = qt0 + w * 16 + kgl * 4 + r;
            o[(size_t)(b * TT + qr) * CC + h * HSZ + dn * 16 + l15] = oa[dn][r] * inv[r];
        }
}

// ---------------- loss ----------------
__global__ void k_zero(float* p) { *p = 0.f; }

__global__ __launch_bounds__(256) void k_loss(const float* __restrict__ logits,
                                              const int* __restrict__ targets,
                                              float* __restrict__ loss) {
    int row = blockIdx.x;
    const float* lr = logits + (size_t)row * VV;
    int tid = threadIdx.x;
    float m = -1e30f, s = 0.f;
    for (int j = tid * 4; j < VV; j += 1024) {
        float4 xv = *(const float4*)(lr + j);
        float xs[4] = {xv.x, xv.y, xv.z, xv.w};
#pragma unroll
        for (int u = 0; u < 4; u++) {
            float mn = fmaxf(m, xs[u]);
            s = s * __expf(m - mn) + __expf(xs[u] - mn);
            m = mn;
        }
    }
#pragma unroll
    for (int off = 32; off; off >>= 1) {
        float m2 = __shfl_xor(m, off);
        float s2 = __shfl_xor(s, off);
        float mn = fmaxf(m, m2);
        s = s * __expf(m - mn) + s2 * __expf(m2 - mn);
        m = mn;
    }
    __shared__ float sm[4], ss[4];
    int wave = tid >> 6, lane = tid & 63;
    if (lane == 0) { sm[wave] = m; ss[wave] = s; }
    __syncthreads();
    if (tid == 0) {
        float M = fmaxf(fmaxf(sm[0], sm[1]), fmaxf(sm[2], sm[3]));
        float S = ss[0] * __expf(sm[0] - M) + ss[1] * __expf(sm[1] - M)
                + ss[2] * __expf(sm[2] - M) + ss[3] * __expf(sm[3] - M);
        float lt = lr[targets[row]];
        atomicAdd(loss, -(lt - M - logf(S)) * (1.0f / (float)MROWS));
    }
}

// ---------------- orchestration ----------------
extern "C" void kernel_launch(void* const* d_in, const int* in_sizes, int n_in,
                              void* d_out, int out_size, void* d_ws, size_t ws_size,
                              hipStream_t stream) {
    const int*   idx   = (const int*)d_in[0];
    const int*   idxl  = (const int*)d_in[1];
    const int*   tgt   = (const int*)d_in[2];
    const float* tok   = (const float*)d_in[3];
    const float* pos   = (const float*)d_in[4];
    const float* lab   = (const float*)d_in[5];
    const float* Wq    = (const float*)d_in[6];
    const float* Wk    = (const float*)d_in[7];
    const float* Wv    = (const float*)d_in[8];
    const float* Wo    = (const float*)d_in[9];
    const float* bo    = (const float*)d_in[10];
    const float* ln1g  = (const float*)d_in[11];
    const float* ln1b  = (const float*)d_in[12];
    const float* W1    = (const float*)d_in[13];
    const float* b1    = (const float*)d_in[14];
    const float* W2    = (const float*)d_in[15];
    const float* b2    = (const float*)d_in[16];
    const float* ln2g  = (const float*)d_in[17];
    const float* ln2b  = (const float*)d_in[18];
    const float* lnfg  = (const float*)d_in[19];
    const float* lnfb  = (const float*)d_in[20];
    const float* Wlm   = (const float*)d_in[21];
    const float* blm   = (const float*)d_in[22];
    float* out = (float*)d_out;
    float* ws  = (float*)d_ws;

    const size_t NTOK = (size_t)MROWS * CC;   // 4,194,304
    float* x  = ws;
    float* h  = x  + NTOK;
    float* qb = h  + NTOK;
    float* kb = qb + NTOK;
    float* vb = kb + NTOK;
    float* ob = vb + NTOK;
    float* ff = ob + NTOK;                    // 8192*2048

    dim3 blk(256);
    dim3 g_sq(CC / 128, MROWS / 128);         // 4  x 64
    dim3 g_ff(FFD / 128, MROWS / 128);        // 16 x 64
    dim3 g_lm(VV / 128, MROWS / 128);         // 64 x 64
    dim3 gs_at(TT / 64, BBATCH * NH);         // 16 x 128

    k_embed<<<MROWS, 128, 0, stream>>>(idx, idxl, tok, pos, lab, x);

    for (int l = 0; l < NL; l++) {
        k_ln<<<MROWS / 4, blk, 0, stream>>>(x, ln1g + l * CC, ln1b + l * CC, h);
        const size_t wqkv = (size_t)l * NH * CC * HSZ;
        k_gemm<0, 0, 1><<<g_sq, blk, 0, stream>>>(h, Wq + wqkv, nullptr, qb, MROWS, CC, CC);
        k_gemm<0, 0, 1><<<g_sq, blk, 0, stream>>>(h, Wk + wqkv, nullptr, kb, MROWS, CC, CC);
        k_gemm<0, 0, 1><<<g_sq, blk, 0, stream>>>(h, Wv + wqkv, nullptr, vb, MROWS, CC, CC);
        k_attn<<<gs_at, blk, 0, stream>>>(qb, kb, vb, ob);
        k_gemm<0, 1, 0><<<g_sq, blk, 0, stream>>>(ob, Wo + (size_t)l * CC * CC,
                                                  bo + l * CC, x, MROWS, CC, CC);
        k_ln<<<MROWS / 4, blk, 0, stream>>>(x, ln2g + l * CC, ln2b + l * CC, h);
        k_gemm<1, 0, 0><<<g_ff, blk, 0, stream>>>(h, W1 + (size_t)l * CC * FFD,
                                                  b1 + l * FFD, ff, MROWS, FFD, CC);
        k_gemm<0, 1, 0><<<g_sq, blk, 0, stream>>>(ff, W2 + (size_t)l * FFD * CC,
                                                  b2 + l * CC, x, MROWS, CC, FFD);
    }

    k_ln<<<MROWS / 4, blk, 0, stream>>>(x, lnfg, lnfb, h);
    k_gemm<0, 0, 0><<<g_lm, blk, 0, stream>>>(h, Wlm, blm, out, MROWS, VV, CC);

    float* loss_p = out + (size_t)MROWS * VV;
    k_zero<<<1, 1, 0, stream>>>(loss_p);
    k_loss<<<MROWS, blk, 0, stream>>>(out, tgt, loss_p);
}